// Round 10
// baseline (175.659 us; speedup 1.0000x reference)
//
#include <hip/hip_runtime.h>

// SegmentTree scatter-update + path propagation.
// capacity C = 2^23, n_updates = 2^20, tree = 2C floats (64 MiB).
//
// R15: merge occupancy fix. R14 post-mortem: hoisting loads did NOT move
// merge (43.9 vs 43.0 us) -> not an ordering problem. Occupancy 51%: only
// ~2 lockstep 1024-thread blocks/CU -> too few independent memory streams
// to hide latency (VALU ~4 us, traffic floor ~17 us, rest = exposed
// latency). Fix: 4x smaller merge blocks (256 thr, 2048 leaves, 4096
// blocks = 8 resident/CU, phase-decoupled).
// bin_kernel stays BYTE-IDENTICAL to R13 (1024 bins, proven ~18 us);
// each merge block scans its whole bin (L3-resident) and keeps its
// quarter (offset>>11 == m&3).
// Ladder: L1..L3 regs, L4..L9 wave shuffles (4 waves), wave0 folds
// L10/L11, publishes L11 value+flag via fence-free atomicExch + ticket
// (R13-proven); last block register-folds 4096 L11 -> L12..L15, then a
// 4-wave shuffle ladder to the root.
// Exact same pairwise sums as reference -> absmax 0.
//
// ws layout:  cnt  uint[1024]        @ 0      (4 KB)
//             done uint              @ 4096
//             l11v uint[4096]        @ 8192   (16 KB)
//             l11f uint[4096]        @ 24576  (16 KB)
//             bins uint2[1024*2048]  @ 65536  (16 MB)

typedef unsigned int uint;
typedef unsigned char uchar;
typedef unsigned long long ull;

#define NBINS 1024
#define BCAP  2048

// bit j of result = (c bit 2j) | (c bit 2j+1), 64-bit
__device__ __forceinline__ ull pc64(ull c) {
    ull x = (c | (c >> 1)) & 0x5555555555555555ull;
    x = (x | (x >> 1))  & 0x3333333333333333ull;
    x = (x | (x >> 2))  & 0x0F0F0F0F0F0F0F0Full;
    x = (x | (x >> 4))  & 0x00FF00FF00FF00FFull;
    x = (x | (x >> 8))  & 0x0000FFFF0000FFFFull;
    x = (x | (x >> 16)) & 0x00000000FFFFFFFFull;
    return x;
}

__global__ __launch_bounds__(1024)
void bin_kernel(const int* __restrict__ idx,
                const float* __restrict__ val,
                uint* __restrict__ cnt,
                uint2* __restrict__ bins) {
    __shared__ uint hist[NBINS];    // histogram, then reused as scatter cursor
    __shared__ uint rbase[NBINS];
    const int tid = threadIdx.x;
    hist[tid] = 0u;
    __syncthreads();

    const int g = blockIdx.x * 1024 + tid;      // int4 units
    int4   j4 = ((const int4*)idx)[g];
    float4 v4 = ((const float4*)val)[g];
    uint  j[4] = { (uint)j4.x, (uint)j4.y, (uint)j4.z, (uint)j4.w };
    float v[4] = { v4.x, v4.y, v4.z, v4.w };

    #pragma unroll
    for (int e = 0; e < 4; ++e) atomicAdd(&hist[j[e] >> 13], 1u);
    __syncthreads();

    uint h = hist[tid];
    rbase[tid] = h ? atomicAdd(&cnt[tid], h) : 0u;
    hist[tid] = 0u;                 // reuse as cursor
    __syncthreads();

    #pragma unroll
    for (int e = 0; e < 4; ++e) {
        uint bin = j[e] >> 13;
        uint r = rbase[bin] + atomicAdd(&hist[bin], 1u);
        if (r < BCAP)
            bins[((size_t)bin << 11) + r] =
                make_uint2(j[e] & 8191u, __float_as_uint(v[e]));
    }
}

// 4096 blocks x 256 threads; block = one 2048-leaf quarter-bin.
// Last block done (atomic ticket, fence-free) also runs the root tail.
__global__ __launch_bounds__(256)
void merge_kernel(const float* __restrict__ tree,
                  const uint* __restrict__ cnt,
                  const uint2* __restrict__ bins,
                  uint* __restrict__ l11v,
                  uint* __restrict__ l11f,
                  uint* __restrict__ done,
                  float* __restrict__ out, int C) {
    __shared__ float slv[2048];     // 8 KB
    __shared__ uchar sfl[2048];     // 2 KB
    __shared__ float s9v[4];
    __shared__ uint  s9d[4];
    __shared__ uint  sticket;
    __shared__ float s16v[16];
    __shared__ uint  s16d[16];

    const int m    = blockIdx.x;        // 2048-leaf block id, 0..4095
    const int b    = m >> 2;            // bin id
    const uint q   = (uint)(m & 3);     // quarter within bin
    const int tid  = threadIdx.x;
    const int wv   = tid >> 6;          // 0..3
    const int lane = tid & 63;
    const int r    = m * 4 + wv;        // 512-leaf region id, 0..16383
    const int leaf0  = tid * 8;
    const int gleaf0 = m * 2048 + leaf0;

    // ---- hoisted address-predetermined loads (kept from R14: harmless,
    //      one drain at barrier 1) ----
    uint c = cnt[b];
    float4 ta = *(const float4*)(tree + C + gleaf0);
    float4 tb = *(const float4*)(tree + C + gleaf0 + 4);
    float4 t1 = *(const float4*)(tree + (C >> 1) + (gleaf0 >> 1));
    float2 t2 = *(const float2*)(tree + (C >> 2) + (gleaf0 >> 2));
    float t3v = tree[(C >> 3) + (gleaf0 >> 3)];
    float pt[6];                        // L4..L9 ladder values, lane-clamped
    #pragma unroll
    for (int lvl = 4; lvl <= 9; ++lvl) {
        int n = 64 >> (lvl - 3);
        pt[lvl - 4] = tree[(C >> lvl) + (r << (9 - lvl)) + (lane & (n - 1))];
    }
    float pu0 = 0.f, pu1 = 0.f;         // wave0: L10 (2 nodes), L11 (1)
    if (wv == 0) {
        pu0 = tree[(C >> 10) + (m << 1) + (lane & 1)];
        pu1 = tree[(C >> 11) + m];
    }

    ((uint2*)sfl)[tid] = make_uint2(0u, 0u);
    ((float2*)slv)[tid] = make_float2(0.f, 0.f);
    ((float2*)slv)[tid + 256] = make_float2(0.f, 0.f);
    ((float2*)slv)[tid + 512] = make_float2(0.f, 0.f);
    ((float2*)slv)[tid + 768] = make_float2(0.f, 0.f);
    __syncthreads();                    // barrier 1

    // ---- gather: scan the whole bin, keep this block's quarter ----
    if (c > BCAP) c = BCAP;
    const uint2* mybin = bins + ((size_t)b << 11);
    for (uint k = tid; k < c; k += 256u) {
        uint2 e = mybin[k];
        if ((e.x >> 11) == q) {
            uint off = e.x & 2047u;
            slv[off] = __uint_as_float(e.y);
            sfl[off] = 1;
        }
    }
    __syncthreads();                    // barrier 2

    uint2 fw = *(const uint2*)&sfl[leaf0];
    float4 la = *(const float4*)&slv[leaf0];
    float4 lb = *(const float4*)&slv[leaf0 + 4];

    float l0 = (fw.x & 0x000000FFu) ? la.x : ta.x;
    float l1 = (fw.x & 0x0000FF00u) ? la.y : ta.y;
    float l2 = (fw.x & 0x00FF0000u) ? la.z : ta.z;
    float l3 = (fw.x & 0xFF000000u) ? la.w : ta.w;
    float l4 = (fw.y & 0x000000FFu) ? lb.x : tb.x;
    float l5 = (fw.y & 0x0000FF00u) ? lb.y : tb.y;
    float l6 = (fw.y & 0x00FF0000u) ? lb.z : tb.z;
    float l7 = (fw.y & 0xFF000000u) ? lb.w : tb.w;

    *(float4*)(out + C + gleaf0)     = make_float4(l0, l1, l2, l3);
    *(float4*)(out + C + gleaf0 + 4) = make_float4(l4, l5, l6, l7);

    // ---- L1..L3 in registers ----
    uint d10 = (fw.x & 0x0000FFFFu) != 0u;
    uint d11 = (fw.x & 0xFFFF0000u) != 0u;
    uint d12 = (fw.y & 0x0000FFFFu) != 0u;
    uint d13 = (fw.y & 0xFFFF0000u) != 0u;
    float4 v1;
    v1.x = d10 ? l0 + l1 : t1.x;
    v1.y = d11 ? l2 + l3 : t1.y;
    v1.z = d12 ? l4 + l5 : t1.z;
    v1.w = d13 ? l6 + l7 : t1.w;
    *(float4*)(out + (C >> 1) + (gleaf0 >> 1)) = v1;

    uint d20 = d10 | d11, d21 = d12 | d13;
    float2 v2;
    v2.x = d20 ? v1.x + v1.y : t2.x;
    v2.y = d21 ? v1.z + v1.w : t2.y;
    *(float2*)(out + (C >> 2) + (gleaf0 >> 2)) = v2;

    uint d3 = d20 | d21;
    float v = d3 ? v2.x + v2.y : t3v;
    out[(C >> 3) + (gleaf0 >> 3)] = v;

    // ---- L4..L9: wave shuffles (wave = 512-leaf region) ----
    ull mk = __ballot(d3 != 0u);
    #pragma unroll
    for (int lvl = 4; lvl <= 9; ++lvl) {
        float a  = __shfl(v, 2 * lane, 64);
        float bb = __shfl(v, 2 * lane + 1, 64);
        mk = pc64(mk);
        int n = 64 >> (lvl - 3);
        if (lane < n) {
            int node = (C >> lvl) + (r << (9 - lvl)) + lane;
            uint dd = (uint)(mk >> lane) & 1u;
            v = dd ? a + bb : pt[lvl - 4];
            out[node] = v;
        }
    }
    if (lane == 0) { s9v[wv] = v; s9d[wv] = (uint)(mk & 1ull); }
    __syncthreads();

    // ---- L10/L11: wave 0 folds 4 L9 values; publish + ticket ----
    if (wv == 0) {
        float vv = lane < 4 ? s9v[lane] : 0.f;
        uint dd  = lane < 4 ? s9d[lane] : 0u;
        ull mm = __ballot(dd != 0u);
        // L10 (2 nodes)
        {
            float a  = __shfl(vv, 2 * lane, 64);
            float bb = __shfl(vv, 2 * lane + 1, 64);
            mm = pc64(mm);
            if (lane < 2) {
                uint d2 = (uint)(mm >> lane) & 1u;
                vv = d2 ? a + bb : pu0;
                out[(C >> 10) + 2 * m + lane] = vv;
            }
        }
        // L11 (1 node)
        {
            float a  = __shfl(vv, 0, 64);
            float bb = __shfl(vv, 1, 64);
            mm = pc64(mm);
            if (lane == 0) {
                uint d2 = (uint)mm & 1u;
                vv = d2 ? a + bb : pu1;
                out[(C >> 11) + m] = vv;
                uint o1 = atomicExch(&l11v[m], __float_as_uint(vv));
                uint o2 = atomicExch(&l11f[m], d2);
                asm volatile("" : : "v"(o1), "v"(o2));   // wait completion
                sticket = atomicAdd(done, 1u);
            }
        }
    }
    __syncthreads();
    if (sticket != (uint)gridDim.x - 1u) return;

    // ---- fused tail (last block, 256 threads): 4096 L11 values -> root.
    //      Reads tree (const) + atomically-published l11v/l11f only. ----
    {
        const int t = tid, w2 = tid >> 6;

        // 16 L11 values + flags per thread (atomic reads = coherent).
        float s11[16]; uint f11[16];
        #pragma unroll
        for (int k = 0; k < 16; ++k) {
            s11[k] = __uint_as_float(atomicOr(&l11v[16 * t + k], 0u));
            f11[k] = atomicOr(&l11f[16 * t + k], 0u);
        }

        // L12 range [2048,4096): 8 nodes/thread.
        float4 tA = *(const float4*)(tree + 2048 + 8 * t);
        float4 tB = *(const float4*)(tree + 2048 + 8 * t + 4);
        float t12_[8] = { tA.x, tA.y, tA.z, tA.w, tB.x, tB.y, tB.z, tB.w };
        float v12[8]; uint d12_[8];
        #pragma unroll
        for (int k = 0; k < 8; ++k) {
            uint d = f11[2 * k] | f11[2 * k + 1];
            d12_[k] = d;
            v12[k]  = d ? s11[2 * k] + s11[2 * k + 1] : t12_[k];
        }
        *(float4*)(out + 2048 + 8 * t)     = make_float4(v12[0], v12[1], v12[2], v12[3]);
        *(float4*)(out + 2048 + 8 * t + 4) = make_float4(v12[4], v12[5], v12[6], v12[7]);

        // L13 range [1024,2048): 4 nodes/thread.
        float4 t13 = *(const float4*)(tree + 1024 + 4 * t);
        float t13_[4] = { t13.x, t13.y, t13.z, t13.w };
        float v13[4]; uint d13_[4];
        #pragma unroll
        for (int k = 0; k < 4; ++k) {
            uint d = d12_[2 * k] | d12_[2 * k + 1];
            d13_[k] = d;
            v13[k]  = d ? v12[2 * k] + v12[2 * k + 1] : t13_[k];
        }
        *(float4*)(out + 1024 + 4 * t) = make_float4(v13[0], v13[1], v13[2], v13[3]);

        // L14 range [512,1024): 2 nodes/thread.
        float2 t14 = *(const float2*)(tree + 512 + 2 * t);
        uint dA = d13_[0] | d13_[1], dB = d13_[2] | d13_[3];
        float vA = dA ? v13[0] + v13[1] : t14.x;
        float vB = dB ? v13[2] + v13[3] : t14.y;
        *(float2*)(out + 512 + 2 * t) = make_float2(vA, vB);

        // L15 range [256,512): 1 node/thread.
        uint d = dA | dB;
        float v15 = d ? vA + vB : tree[256 + t];
        out[256 + t] = v15;

        // M = 128..16: 4-wave shuffle ladder (nw = M/4 nodes per wave).
        float tv = v15;
        ull m2 = __ballot(d != 0u);
        #pragma unroll
        for (int M = 128; M >= 16; M >>= 1) {
            float a  = __shfl(tv, 2 * lane, 64);
            float bb = __shfl(tv, 2 * lane + 1, 64);
            m2 = pc64(m2);
            int nw = M >> 2;
            if (lane < nw) {
                int node = M + nw * w2 + lane;
                uint dd = (uint)(m2 >> lane) & 1u;
                tv = dd ? a + bb : tree[node];
                out[node] = tv;
            }
        }
        if (lane < 4) { s16v[4 * w2 + lane] = tv;
                        s16d[4 * w2 + lane] = (uint)(m2 >> lane) & 1u; }
        __syncthreads();

        if (w2 == 0) {
            float vv = lane < 16 ? s16v[lane] : 0.f;
            uint dd  = lane < 16 ? s16d[lane] : 0u;
            ull mm = __ballot(dd != 0u);
            #pragma unroll
            for (int M = 8; M >= 1; M >>= 1) {
                float a  = __shfl(vv, 2 * lane, 64);
                float bb = __shfl(vv, 2 * lane + 1, 64);
                mm = pc64(mm);
                if (lane < M) {
                    uint d2 = (uint)(mm >> lane) & 1u;
                    vv = d2 ? a + bb : tree[M + lane];
                    out[M + lane] = vv;
                }
            }
            if (lane == 0) out[0] = tree[0];
        }
    }
}

extern "C" void kernel_launch(void* const* d_in, const int* in_sizes, int n_in,
                              void* d_out, int out_size, void* d_ws, size_t ws_size,
                              hipStream_t stream) {
    const float* tree    = (const float*)d_in[0];
    const int*   indices = (const int*)d_in[1];
    const float* values  = (const float*)d_in[2];
    float* out = (float*)d_out;

    const int two_cap = in_sizes[0];     // 16,777,216
    const int C       = two_cap >> 1;    // 8,388,608
    const int nupd    = in_sizes[1];     // 1,048,576

    uchar* ws = (uchar*)d_ws;
    uint*  cnt  = (uint*)ws;                 // 4 KB
    uint*  done = (uint*)(ws + 4096);        // 4 B
    uint*  l11v = (uint*)(ws + 8192);        // 16 KB
    uint*  l11f = (uint*)(ws + 24576);       // 16 KB
    uint2* bins = (uint2*)(ws + 65536);      // 16 MB

    hipMemsetAsync(ws, 0, 4160, stream);     // cnt + done
    bin_kernel<<<nupd / 4096, 1024, 0, stream>>>(indices, values, cnt, bins);
    merge_kernel<<<C / 2048, 256, 0, stream>>>(tree, cnt, bins, l11v, l11f,
                                               done, out, C);
}

// Round 11
// 154.655 us; speedup vs baseline: 1.1358x; 1.1358x over previous
//
#include <hip/hip_runtime.h>

// SegmentTree scatter-update + path propagation.
// capacity C = 2^23, n_updates = 2^20, tree = 2C floats (64 MiB).
//
// R16: merge ILP fix. History: R13/R14 merge = 43 us (2.4 TB/s, latency-
// bound); R14 hoist = neutral (ordering theory dead); R15 256-thr quarter-
// bins = 72 us REGRESSION (occupancy theory dead: occupancy rose, perf
// fell; quarter-scan re-read bins 4x at ~0.5 TB/s marginal BW + mean-4
// serialized gather iterations). Surviving hypothesis: per-thread memory
// ILP with single-pass gather.
// This version: bin kernel + ticket/publish/tail machinery byte-identical
// to R13. Merge: 1024 blocks x 256 threads (40 KB LDS -> 4 blocks/CU,
// whole grid co-resident), block = one 8192-leaf bin:
//   - gather: single pass, uint4 (2 entries/load), mean 2 iterations;
//   - leaf/L1..L3: R13's register code x4 chunks (it*2048 + tid*8) ->
//     ~8 independent load streams per thread;
//   - L4..L9: 4 INTERLEAVED shuffle ladders (4 masked tree loads in
//     flight per level), 16 L9 values in s9v (region order preserved);
//   - L10..L13 + publish + ticket: R13's exact wave-0 code;
//   - tail (last block, 256 thr): 4 L13/thread -> L14/L15 in registers,
//     M=128..16 4-wave ladder, wave 0 finishes M=8..1.
// Exact same pairwise sums as reference -> absmax 0.
//
// ws layout:  cnt  uint[1024]        @ 0      (4 KB)
//             done uint              @ 4096
//             l13v uint[1024]        @ 8192   (4 KB)
//             l13f uint[1024]        @ 12288  (4 KB)
//             bins uint2[1024*2048]  @ 32768  (16 MB)

typedef unsigned int uint;
typedef unsigned char uchar;
typedef unsigned long long ull;

#define NBINS 1024
#define BCAP  2048

// bit j of result = (c bit 2j) | (c bit 2j+1), 64-bit
__device__ __forceinline__ ull pc64(ull c) {
    ull x = (c | (c >> 1)) & 0x5555555555555555ull;
    x = (x | (x >> 1))  & 0x3333333333333333ull;
    x = (x | (x >> 2))  & 0x0F0F0F0F0F0F0F0Full;
    x = (x | (x >> 4))  & 0x00FF00FF00FF00FFull;
    x = (x | (x >> 8))  & 0x0000FFFF0000FFFFull;
    x = (x | (x >> 16)) & 0x00000000FFFFFFFFull;
    return x;
}

__global__ __launch_bounds__(1024)
void bin_kernel(const int* __restrict__ idx,
                const float* __restrict__ val,
                uint* __restrict__ cnt,
                uint2* __restrict__ bins) {
    __shared__ uint hist[NBINS];    // histogram, then reused as scatter cursor
    __shared__ uint rbase[NBINS];
    const int tid = threadIdx.x;
    hist[tid] = 0u;
    __syncthreads();

    const int g = blockIdx.x * 1024 + tid;      // int4 units
    int4   j4 = ((const int4*)idx)[g];
    float4 v4 = ((const float4*)val)[g];
    uint  j[4] = { (uint)j4.x, (uint)j4.y, (uint)j4.z, (uint)j4.w };
    float v[4] = { v4.x, v4.y, v4.z, v4.w };

    #pragma unroll
    for (int e = 0; e < 4; ++e) atomicAdd(&hist[j[e] >> 13], 1u);
    __syncthreads();

    uint h = hist[tid];
    rbase[tid] = h ? atomicAdd(&cnt[tid], h) : 0u;
    hist[tid] = 0u;                 // reuse as cursor
    __syncthreads();

    #pragma unroll
    for (int e = 0; e < 4; ++e) {
        uint bin = j[e] >> 13;
        uint r = rbase[bin] + atomicAdd(&hist[bin], 1u);
        if (r < BCAP)
            bins[((size_t)bin << 11) + r] =
                make_uint2(j[e] & 8191u, __float_as_uint(v[e]));
    }
}

// 1024 blocks x 256 threads; block = one 8192-leaf bin. Last block done
// (atomic ticket, fence-free) also runs the root tail.
__global__ __launch_bounds__(256)
void merge_kernel(const float* __restrict__ tree,
                  const uint* __restrict__ cnt,
                  const uint2* __restrict__ bins,
                  uint* __restrict__ l13v,
                  uint* __restrict__ l13f,
                  uint* __restrict__ done,
                  float* __restrict__ out, int C) {
    __shared__ float slv[8192];     // 32 KB
    __shared__ uint  sflw[2048];    // 8 KB of flag bytes
    __shared__ float s9v[16];
    __shared__ uint  s9d[16];
    __shared__ uint  sticket;
    __shared__ float s16v[16];
    __shared__ uint  s16d[16];

    const int b    = blockIdx.x;
    const int tid  = threadIdx.x;
    const int wv   = tid >> 6;
    const int lane = tid & 63;
    uchar* sfl = (uchar*)sflw;

    #pragma unroll
    for (int i = 0; i < 8; ++i) sflw[i * 256 + tid] = 0u;
    __syncthreads();

    // ---- gather: single pass over this bin, 2 entries per uint4 load ----
    uint c = cnt[b];
    if (c > BCAP) c = BCAP;
    const uint2* mybin  = bins + ((size_t)b << 11);
    const uint4* mybin4 = (const uint4*)mybin;
    for (uint k = tid; k < (c >> 1); k += 256u) {
        uint4 e2 = mybin4[k];
        slv[e2.x] = __uint_as_float(e2.y);
        sfl[e2.x] = 1;
        slv[e2.z] = __uint_as_float(e2.w);
        sfl[e2.z] = 1;
    }
    if ((c & 1u) && tid == 0) {
        uint2 e = mybin[c - 1];
        slv[e.x] = __uint_as_float(e.y);
        sfl[e.x] = 1;
    }
    __syncthreads();

    // ---- 4 chunks per thread: chunk it = leaves [it*2048+tid*8, +8) ----
    float vL[4];            // per-chunk L3 value
    ull   mk[4];            // per-chunk ballot masks
    #pragma unroll
    for (int it = 0; it < 4; ++it) {
        const int leaf0  = it * 2048 + tid * 8;
        const int gleaf0 = b * 8192 + leaf0;

        uint2 fw = *(const uint2*)&sfl[leaf0];
        float4 la = *(const float4*)&slv[leaf0];
        float4 lb = *(const float4*)&slv[leaf0 + 4];
        float4 ta = *(const float4*)(tree + C + gleaf0);
        float4 tb = *(const float4*)(tree + C + gleaf0 + 4);

        float l0 = (fw.x & 0x000000FFu) ? la.x : ta.x;
        float l1 = (fw.x & 0x0000FF00u) ? la.y : ta.y;
        float l2 = (fw.x & 0x00FF0000u) ? la.z : ta.z;
        float l3 = (fw.x & 0xFF000000u) ? la.w : ta.w;
        float l4 = (fw.y & 0x000000FFu) ? lb.x : tb.x;
        float l5 = (fw.y & 0x0000FF00u) ? lb.y : tb.y;
        float l6 = (fw.y & 0x00FF0000u) ? lb.z : tb.z;
        float l7 = (fw.y & 0xFF000000u) ? lb.w : tb.w;

        *(float4*)(out + C + gleaf0)     = make_float4(l0, l1, l2, l3);
        *(float4*)(out + C + gleaf0 + 4) = make_float4(l4, l5, l6, l7);

        uint d10 = (fw.x & 0x0000FFFFu) != 0u;
        uint d11 = (fw.x & 0xFFFF0000u) != 0u;
        uint d12 = (fw.y & 0x0000FFFFu) != 0u;
        uint d13 = (fw.y & 0xFFFF0000u) != 0u;
        float4 t1 = *(const float4*)(tree + (C >> 1) + (gleaf0 >> 1));
        float4 v1;
        v1.x = d10 ? l0 + l1 : t1.x;
        v1.y = d11 ? l2 + l3 : t1.y;
        v1.z = d12 ? l4 + l5 : t1.z;
        v1.w = d13 ? l6 + l7 : t1.w;
        *(float4*)(out + (C >> 1) + (gleaf0 >> 1)) = v1;

        float2 t2 = *(const float2*)(tree + (C >> 2) + (gleaf0 >> 2));
        uint d20 = d10 | d11, d21 = d12 | d13;
        float2 v2;
        v2.x = d20 ? v1.x + v1.y : t2.x;
        v2.y = d21 ? v1.z + v1.w : t2.y;
        *(float2*)(out + (C >> 2) + (gleaf0 >> 2)) = v2;

        float t3v = tree[(C >> 3) + (gleaf0 >> 3)];
        uint d3 = d20 | d21;
        float v = d3 ? v2.x + v2.y : t3v;
        out[(C >> 3) + (gleaf0 >> 3)] = v;

        vL[it] = v;
        mk[it] = __ballot(d3 != 0u);
    }

    // ---- L4..L9: 4 interleaved shuffle ladders (region r = b*16+it*4+wv) ----
    #pragma unroll
    for (int lvl = 4; lvl <= 9; ++lvl) {
        int n = 64 >> (lvl - 3);
        #pragma unroll
        for (int it = 0; it < 4; ++it) {
            float a  = __shfl(vL[it], 2 * lane, 64);
            float bb = __shfl(vL[it], 2 * lane + 1, 64);
            mk[it] = pc64(mk[it]);
            if (lane < n) {
                int r = b * 16 + it * 4 + wv;
                int node = (C >> lvl) + (r << (9 - lvl)) + lane;
                uint dd = (uint)(mk[it] >> lane) & 1u;
                vL[it] = dd ? a + bb : tree[node];
                out[node] = vL[it];
            }
        }
    }
    if (lane == 0) {
        #pragma unroll
        for (int it = 0; it < 4; ++it) {
            s9v[it * 4 + wv] = vL[it];
            s9d[it * 4 + wv] = (uint)(mk[it] & 1ull);
        }
    }
    __syncthreads();

    // ---- L10..L13: wave 0 folds the block's 16 L9 values (R13 code),
    //      publishes L13 via fence-free atomics + ticket ----
    if (wv == 0) {
        float vv = lane < 16 ? s9v[lane] : 0.f;
        uint dd  = lane < 16 ? s9d[lane] : 0u;
        ull mm = __ballot(dd != 0u);
        #pragma unroll
        for (int lvl = 10; lvl <= 13; ++lvl) {
            float a  = __shfl(vv, 2 * lane, 64);
            float bb = __shfl(vv, 2 * lane + 1, 64);
            mm = pc64(mm);
            int n = 1 << (13 - lvl);        // 8,4,2,1
            if (lane < n) {
                int node = (C >> lvl) + (b << (13 - lvl)) + lane;
                uint d2 = (uint)(mm >> lane) & 1u;
                vv = d2 ? a + bb : tree[node];
                out[node] = vv;
            }
        }
        if (lane == 0) {
            uint o1 = atomicExch(&l13v[b], __float_as_uint(vv));
            uint o2 = atomicExch(&l13f[b], (uint)(mm & 1ull));
            asm volatile("" : : "v"(o1), "v"(o2));   // wait for completion
            sticket = atomicAdd(done, 1u);
        }
    }
    __syncthreads();
    if (sticket != (uint)gridDim.x - 1u) return;

    // ---- fused tail (last block, 256 threads): 1024 L13 values -> root.
    //      Reads tree (const) + atomically-published l13v/l13f only. ----
    {
        const int w2 = tid >> 6;
        float s13[4]; uint f13[4];
        #pragma unroll
        for (int k = 0; k < 4; ++k) {
            s13[k] = __uint_as_float(atomicOr(&l13v[4 * tid + k], 0u));
            f13[k] = atomicOr(&l13f[4 * tid + k], 0u);
        }

        // L14 nodes [512,1024): 2/thread.
        float2 t14 = *(const float2*)(tree + 512 + 2 * tid);
        uint dA = f13[0] | f13[1], dB = f13[2] | f13[3];
        float vA = dA ? s13[0] + s13[1] : t14.x;
        float vB = dB ? s13[2] + s13[3] : t14.y;
        *(float2*)(out + 512 + 2 * tid) = make_float2(vA, vB);

        // L15 nodes [256,512): 1/thread.
        uint d = dA | dB;
        float tv = d ? vA + vB : tree[256 + tid];
        out[256 + tid] = tv;

        // M = 128..16: 4-wave ballot ladder (nw = M/4 nodes per wave).
        ull m2 = __ballot(d != 0u);
        #pragma unroll
        for (int M = 128; M >= 16; M >>= 1) {
            float a  = __shfl(tv, 2 * lane, 64);
            float bb = __shfl(tv, 2 * lane + 1, 64);
            m2 = pc64(m2);
            int nw = M >> 2;
            if (lane < nw) {
                int node = M + nw * w2 + lane;
                uint dd = (uint)(m2 >> lane) & 1u;
                tv = dd ? a + bb : tree[node];
                out[node] = tv;
            }
        }
        if (lane < 4) { s16v[4 * w2 + lane] = tv;
                        s16d[4 * w2 + lane] = (uint)(m2 >> lane) & 1u; }
        __syncthreads();

        if (w2 == 0) {
            float vv = lane < 16 ? s16v[lane] : 0.f;
            uint dd  = lane < 16 ? s16d[lane] : 0u;
            ull mm = __ballot(dd != 0u);
            #pragma unroll
            for (int M = 8; M >= 1; M >>= 1) {
                float a  = __shfl(vv, 2 * lane, 64);
                float bb = __shfl(vv, 2 * lane + 1, 64);
                mm = pc64(mm);
                if (lane < M) {
                    uint d2 = (uint)(mm >> lane) & 1u;
                    vv = d2 ? a + bb : tree[M + lane];
                    out[M + lane] = vv;
                }
            }
            if (lane == 0) out[0] = tree[0];
        }
    }
}

extern "C" void kernel_launch(void* const* d_in, const int* in_sizes, int n_in,
                              void* d_out, int out_size, void* d_ws, size_t ws_size,
                              hipStream_t stream) {
    const float* tree    = (const float*)d_in[0];
    const int*   indices = (const int*)d_in[1];
    const float* values  = (const float*)d_in[2];
    float* out = (float*)d_out;

    const int two_cap = in_sizes[0];     // 16,777,216
    const int C       = two_cap >> 1;    // 8,388,608
    const int nupd    = in_sizes[1];     // 1,048,576

    uchar* ws = (uchar*)d_ws;
    uint*  cnt  = (uint*)ws;                 // 4 KB
    uint*  done = (uint*)(ws + 4096);        // 4 B
    uint*  l13v = (uint*)(ws + 8192);        // 4 KB
    uint*  l13f = (uint*)(ws + 12288);       // 4 KB
    uint2* bins = (uint2*)(ws + 32768);      // 16 MB

    hipMemsetAsync(ws, 0, 4160, stream);     // cnt + done
    bin_kernel<<<nupd / 4096, 1024, 0, stream>>>(indices, values, cnt, bins);
    merge_kernel<<<NBINS, 256, 0, stream>>>(tree, cnt, bins, l13v, l13f,
                                            done, out, C);
}

// Round 13
// 147.981 us; speedup vs baseline: 1.1870x; 1.0451x over previous
//
#include <hip/hip_runtime.h>

// SegmentTree scatter-update + path propagation.
// capacity C = 2^23, n_updates = 2^20, tree = 2C floats (64 MiB).
//
// R17b: fix of R17 compile error -- __builtin_nontemporal_* requires native
// vector types, not HIP_vector_type<float,N>. Use ext_vector_type aliases.
// Theory unchanged (untested): merge (43 us @ 2.4 TB/s; insensitive to
// ordering/occupancy/ILP across R13-R16) is L2 write-allocate thrash --
// 100% single-use streams (tree read once, bins once, out written once),
// the 66 MB out stream evicts tree/bins lines from 4 MB/XCD L2 before
// their loads land. Fix: nontemporal stores for all bulk out writes +
// nontemporal loads for the 32 MB tree-leaf reads. Bins + upper-tree
// reads stay cached (L3-friendly). Everything else byte-identical to R14c.
// Exact same pairwise sums as reference -> absmax 0.
//
// ws layout:  cnt  uint[1024]        @ 0      (4 KB)
//             done uint              @ 4096
//             l13v uint[1024]        @ 8192   (4 KB)
//             l13f uint[1024]        @ 12288  (4 KB)
//             bins uint2[1024*2048]  @ 32768  (16 MB)

typedef unsigned int uint;
typedef unsigned char uchar;
typedef unsigned long long ull;

typedef float vfloat4 __attribute__((ext_vector_type(4)));
typedef float vfloat2 __attribute__((ext_vector_type(2)));

#define NBINS 1024
#define BCAP  2048

__device__ __forceinline__ void nt_store4(float* p, float4 v) {
    vfloat4 t = { v.x, v.y, v.z, v.w };
    __builtin_nontemporal_store(t, (vfloat4*)p);
}
__device__ __forceinline__ void nt_store2(float* p, float2 v) {
    vfloat2 t = { v.x, v.y };
    __builtin_nontemporal_store(t, (vfloat2*)p);
}
__device__ __forceinline__ void nt_store1(float* p, float v) {
    __builtin_nontemporal_store(v, p);
}
__device__ __forceinline__ float4 nt_load4(const float* p) {
    vfloat4 t = __builtin_nontemporal_load((const vfloat4*)p);
    return make_float4(t.x, t.y, t.z, t.w);
}

// bit j of result = (c bit 2j) | (c bit 2j+1), 64-bit
__device__ __forceinline__ ull pc64(ull c) {
    ull x = (c | (c >> 1)) & 0x5555555555555555ull;
    x = (x | (x >> 1))  & 0x3333333333333333ull;
    x = (x | (x >> 2))  & 0x0F0F0F0F0F0F0F0Full;
    x = (x | (x >> 4))  & 0x00FF00FF00FF00FFull;
    x = (x | (x >> 8))  & 0x0000FFFF0000FFFFull;
    x = (x | (x >> 16)) & 0x00000000FFFFFFFFull;
    return x;
}

__global__ __launch_bounds__(1024)
void bin_kernel(const int* __restrict__ idx,
                const float* __restrict__ val,
                uint* __restrict__ cnt,
                uint2* __restrict__ bins) {
    __shared__ uint hist[NBINS];    // histogram, then reused as scatter cursor
    __shared__ uint rbase[NBINS];
    const int tid = threadIdx.x;
    hist[tid] = 0u;
    __syncthreads();

    const int g = blockIdx.x * 1024 + tid;      // int4 units
    int4   j4 = ((const int4*)idx)[g];
    float4 v4 = ((const float4*)val)[g];
    uint  j[4] = { (uint)j4.x, (uint)j4.y, (uint)j4.z, (uint)j4.w };
    float v[4] = { v4.x, v4.y, v4.z, v4.w };

    #pragma unroll
    for (int e = 0; e < 4; ++e) atomicAdd(&hist[j[e] >> 13], 1u);
    __syncthreads();

    uint h = hist[tid];
    rbase[tid] = h ? atomicAdd(&cnt[tid], h) : 0u;
    hist[tid] = 0u;                 // reuse as cursor
    __syncthreads();

    #pragma unroll
    for (int e = 0; e < 4; ++e) {
        uint bin = j[e] >> 13;
        uint r = rbase[bin] + atomicAdd(&hist[bin], 1u);
        if (r < BCAP)
            bins[((size_t)bin << 11) + r] =
                make_uint2(j[e] & 8191u, __float_as_uint(v[e]));
    }
}

// 1024 blocks x 1024 threads; block = one 8192-leaf bin. Last block done
// (atomic ticket, fence-free) also runs the root tail.
__global__ __launch_bounds__(1024)
void merge_kernel(const float* __restrict__ tree,
                  const uint* __restrict__ cnt,
                  const uint2* __restrict__ bins,
                  uint* __restrict__ l13v,
                  uint* __restrict__ l13f,
                  uint* __restrict__ done,
                  float* __restrict__ out, int C) {
    __shared__ float slv[8192];     // 32 KB
    __shared__ uchar sfl[8192];     // 8 KB
    __shared__ float s9v[16];
    __shared__ uint  s9d[16];
    __shared__ uint  sticket;
    __shared__ float s16v[16];
    __shared__ uint  s16d[16];

    const int b    = blockIdx.x;
    const int tid  = threadIdx.x;
    const int wv   = tid >> 6;
    const int lane = tid & 63;
    const int r    = b * 16 + wv;       // 512-leaf region id
    const int leaf0  = tid * 8;
    const int gleaf0 = b * 8192 + leaf0;

    // ---- issue ALL address-predetermined loads up front (one round trip,
    //      drained together at barrier 1). Leaf reads are nontemporal
    //      (single-use stream, keep them out of L2). ----
    uint c = cnt[b];
    float4 ta = nt_load4(tree + C + gleaf0);
    float4 tb = nt_load4(tree + C + gleaf0 + 4);
    float4 t1 = *(const float4*)(tree + (C >> 1) + (gleaf0 >> 1));
    float2 t2 = *(const float2*)(tree + (C >> 2) + (gleaf0 >> 2));
    float t3v = tree[(C >> 3) + (gleaf0 >> 3)];
    float pt[6];                        // L4..L9 ladder values, lane-clamped
    #pragma unroll
    for (int lvl = 4; lvl <= 9; ++lvl) {
        int n = 64 >> (lvl - 3);
        pt[lvl - 4] = tree[(C >> lvl) + (r << (9 - lvl)) + (lane & (n - 1))];
    }
    float pu[4] = {0.f, 0.f, 0.f, 0.f}; // wave0: L10..L13 values
    if (wv == 0) {
        #pragma unroll
        for (int lvl = 10; lvl <= 13; ++lvl) {
            int n = 1 << (13 - lvl);    // 8,4,2,1
            pu[lvl - 10] =
                tree[(C >> lvl) + (b << (13 - lvl)) + (lane & (n - 1))];
        }
    }

    ((uint2*)sfl)[tid] = make_uint2(0u, 0u);
    __syncthreads();                    // barrier 1 (drains hoisted loads)

    if (c > BCAP) c = BCAP;
    const uint2* mybin = bins + ((size_t)b << 11);
    for (uint k = tid; k < c; k += 1024u) {
        uint2 e = mybin[k];
        slv[e.x] = __uint_as_float(e.y);
        sfl[e.x] = 1;
    }
    __syncthreads();                    // barrier 2 (drains gather)

    uint2 fw = *(const uint2*)&sfl[leaf0];
    float4 la = *(const float4*)&slv[leaf0];
    float4 lb = *(const float4*)&slv[leaf0 + 4];

    float l0 = (fw.x & 0x000000FFu) ? la.x : ta.x;
    float l1 = (fw.x & 0x0000FF00u) ? la.y : ta.y;
    float l2 = (fw.x & 0x00FF0000u) ? la.z : ta.z;
    float l3 = (fw.x & 0xFF000000u) ? la.w : ta.w;
    float l4 = (fw.y & 0x000000FFu) ? lb.x : tb.x;
    float l5 = (fw.y & 0x0000FF00u) ? lb.y : tb.y;
    float l6 = (fw.y & 0x00FF0000u) ? lb.z : tb.z;
    float l7 = (fw.y & 0xFF000000u) ? lb.w : tb.w;

    nt_store4(out + C + gleaf0,     make_float4(l0, l1, l2, l3));
    nt_store4(out + C + gleaf0 + 4, make_float4(l4, l5, l6, l7));

    // ---- L1..L3 in registers (tree values preloaded) ----
    uint d10 = (fw.x & 0x0000FFFFu) != 0u;
    uint d11 = (fw.x & 0xFFFF0000u) != 0u;
    uint d12 = (fw.y & 0x0000FFFFu) != 0u;
    uint d13 = (fw.y & 0xFFFF0000u) != 0u;
    float4 v1;
    v1.x = d10 ? l0 + l1 : t1.x;
    v1.y = d11 ? l2 + l3 : t1.y;
    v1.z = d12 ? l4 + l5 : t1.z;
    v1.w = d13 ? l6 + l7 : t1.w;
    nt_store4(out + (C >> 1) + (gleaf0 >> 1), v1);

    uint d20 = d10 | d11, d21 = d12 | d13;
    float2 v2;
    v2.x = d20 ? v1.x + v1.y : t2.x;
    v2.y = d21 ? v1.z + v1.w : t2.y;
    nt_store2(out + (C >> 2) + (gleaf0 >> 2), v2);

    uint d3 = d20 | d21;
    float v = d3 ? v2.x + v2.y : t3v;
    nt_store1(out + (C >> 3) + (gleaf0 >> 3), v);

    // ---- L4..L9: wave shuffles, tree values preloaded in pt[] ----
    ull m = __ballot(d3 != 0u);
    #pragma unroll
    for (int lvl = 4; lvl <= 9; ++lvl) {
        float a  = __shfl(v, 2 * lane, 64);
        float bb = __shfl(v, 2 * lane + 1, 64);
        m = pc64(m);
        int n = 64 >> (lvl - 3);
        if (lane < n) {
            int node = (C >> lvl) + (r << (9 - lvl)) + lane;
            uint dd = (uint)(m >> lane) & 1u;
            v = dd ? a + bb : pt[lvl - 4];  // clean nodes carry tree value
            nt_store1(out + node, v);
        }
    }
    if (lane == 0) { s9v[wv] = v; s9d[wv] = (uint)(m & 1ull); }
    __syncthreads();

    // ---- L10..L13: wave 0 finishes the block's 16 L9 values, then
    //      publishes via device atomics (fence-free) and takes a ticket ----
    if (wv == 0) {
        float vv = lane < 16 ? s9v[lane] : 0.f;
        uint dd  = lane < 16 ? s9d[lane] : 0u;
        ull mm = __ballot(dd != 0u);
        #pragma unroll
        for (int lvl = 10; lvl <= 13; ++lvl) {
            float a  = __shfl(vv, 2 * lane, 64);
            float bb = __shfl(vv, 2 * lane + 1, 64);
            mm = pc64(mm);
            int n = 1 << (13 - lvl);        // 8,4,2,1
            if (lane < n) {
                int node = (C >> lvl) + (b << (13 - lvl)) + lane;
                uint d2 = (uint)(mm >> lane) & 1u;
                vv = d2 ? a + bb : pu[lvl - 10];
                out[node] = vv;
            }
        }
        if (lane == 0) {
            uint o1 = atomicExch(&l13v[b], __float_as_uint(vv));
            uint o2 = atomicExch(&l13f[b], (uint)(mm & 1ull));
            asm volatile("" : : "v"(o1), "v"(o2));   // wait for completion
            sticket = atomicAdd(done, 1u);
        }
    }
    __syncthreads();
    if (sticket != (uint)gridDim.x - 1u) return;

    // ---- fused tail (last block only): ladder 1024 L13 values to root.
    //      Reads ONLY tree (const input) + atomically-published l13v/l13f.
    {
        const int w2 = tid >> 6;
        float tv = __uint_as_float(atomicOr(&l13v[tid], 0u));  // coherent read
        uint  td = atomicOr(&l13f[tid], 0u);

        ull m2 = __ballot(td != 0u);
        #pragma unroll
        for (int M = 512; M >= 16; M >>= 1) {
            float a  = __shfl(tv, 2 * lane, 64);
            float bb = __shfl(tv, 2 * lane + 1, 64);
            m2 = pc64(m2);
            int nw = M >> 4;
            if (lane < nw) {
                int node = M + nw * w2 + lane;
                uint dd = (uint)(m2 >> lane) & 1u;
                tv = dd ? a + bb : tree[node];
                out[node] = tv;
            }
        }
        if (lane == 0) { s16v[w2] = tv; s16d[w2] = (uint)(m2 & 1ull); }
        __syncthreads();

        if (w2 == 0) {
            float vv2 = lane < 16 ? s16v[lane] : 0.f;
            uint dd2  = lane < 16 ? s16d[lane] : 0u;
            ull mm2 = __ballot(dd2 != 0u);
            #pragma unroll
            for (int M = 8; M >= 1; M >>= 1) {
                float a  = __shfl(vv2, 2 * lane, 64);
                float bb = __shfl(vv2, 2 * lane + 1, 64);
                mm2 = pc64(mm2);
                if (lane < M) {
                    uint d2 = (uint)(mm2 >> lane) & 1u;
                    vv2 = d2 ? a + bb : tree[M + lane];
                    out[M + lane] = vv2;
                }
            }
            if (lane == 0) out[0] = tree[0];
        }
    }
}

extern "C" void kernel_launch(void* const* d_in, const int* in_sizes, int n_in,
                              void* d_out, int out_size, void* d_ws, size_t ws_size,
                              hipStream_t stream) {
    const float* tree    = (const float*)d_in[0];
    const int*   indices = (const int*)d_in[1];
    const float* values  = (const float*)d_in[2];
    float* out = (float*)d_out;

    const int two_cap = in_sizes[0];     // 16,777,216
    const int C       = two_cap >> 1;    // 8,388,608
    const int nupd    = in_sizes[1];     // 1,048,576

    uchar* ws = (uchar*)d_ws;
    uint*  cnt  = (uint*)ws;                 // 4 KB
    uint*  done = (uint*)(ws + 4096);        // 4 B
    uint*  l13v = (uint*)(ws + 8192);        // 4 KB
    uint*  l13f = (uint*)(ws + 12288);       // 4 KB
    uint2* bins = (uint2*)(ws + 32768);      // 16 MB

    (void)hipMemsetAsync(ws, 0, 4160, stream);   // cnt + done
    bin_kernel<<<nupd / 4096, 1024, 0, stream>>>(indices, values, cnt, bins);
    merge_kernel<<<C / 8192, 1024, 0, stream>>>(tree, cnt, bins, l13v, l13f,
                                                done, out, C);
}

// Round 14
// 144.965 us; speedup vs baseline: 1.2117x; 1.0208x over previous
//
#include <hip/hip_runtime.h>

// SegmentTree scatter-update + path propagation.
// capacity C = 2^23, n_updates = 2^20, tree = 2C floats (64 MiB).
//
// R18: LDS-residency fix on R14c (best: 144.3 us). R17b falsified the
// write-thrash theory (NT stores: +27 MB writes, 3.17 TB/s, SAME 43 us ->
// spare BW exists). The overlooked counter: LDS_Block_Size=41472 ->
// 160KiB/41472 = 3 resident blocks/CU, but grid = 1024/256 = 4 per CU ->
// merge runs 3 co-resident rounds + a 256-block straggler round at
// 1 block/CU, and the fused tail waits for the stragglers. (Also explains
// R16's 19% occupancy: same LDS, 256-thr blocks -> 12/64 wave slots.)
// Fix: sfl byte-array (8 KB) -> bit-field sflb[256] (1 KB, LDS atomicOr)
// => LDS ~34.1 KB => 4 blocks/CU, whole grid co-resident, one round.
// Everything else byte-identical to R14c (bin kernel, hoisted loads,
// ticket+atomic-publish fused tail).
// Exact same pairwise sums as reference -> absmax 0.
//
// ws layout:  cnt  uint[1024]        @ 0      (4 KB)
//             done uint              @ 4096
//             l13v uint[1024]        @ 8192   (4 KB)
//             l13f uint[1024]        @ 12288  (4 KB)
//             bins uint2[1024*2048]  @ 32768  (16 MB)

typedef unsigned int uint;
typedef unsigned char uchar;
typedef unsigned long long ull;

#define NBINS 1024
#define BCAP  2048

// bit j of result = (c bit 2j) | (c bit 2j+1), 64-bit
__device__ __forceinline__ ull pc64(ull c) {
    ull x = (c | (c >> 1)) & 0x5555555555555555ull;
    x = (x | (x >> 1))  & 0x3333333333333333ull;
    x = (x | (x >> 2))  & 0x0F0F0F0F0F0F0F0Full;
    x = (x | (x >> 4))  & 0x00FF00FF00FF00FFull;
    x = (x | (x >> 8))  & 0x0000FFFF0000FFFFull;
    x = (x | (x >> 16)) & 0x00000000FFFFFFFFull;
    return x;
}

__global__ __launch_bounds__(1024)
void bin_kernel(const int* __restrict__ idx,
                const float* __restrict__ val,
                uint* __restrict__ cnt,
                uint2* __restrict__ bins) {
    __shared__ uint hist[NBINS];    // histogram, then reused as scatter cursor
    __shared__ uint rbase[NBINS];
    const int tid = threadIdx.x;
    hist[tid] = 0u;
    __syncthreads();

    const int g = blockIdx.x * 1024 + tid;      // int4 units
    int4   j4 = ((const int4*)idx)[g];
    float4 v4 = ((const float4*)val)[g];
    uint  j[4] = { (uint)j4.x, (uint)j4.y, (uint)j4.z, (uint)j4.w };
    float v[4] = { v4.x, v4.y, v4.z, v4.w };

    #pragma unroll
    for (int e = 0; e < 4; ++e) atomicAdd(&hist[j[e] >> 13], 1u);
    __syncthreads();

    uint h = hist[tid];
    rbase[tid] = h ? atomicAdd(&cnt[tid], h) : 0u;
    hist[tid] = 0u;                 // reuse as cursor
    __syncthreads();

    #pragma unroll
    for (int e = 0; e < 4; ++e) {
        uint bin = j[e] >> 13;
        uint r = rbase[bin] + atomicAdd(&hist[bin], 1u);
        if (r < BCAP)
            bins[((size_t)bin << 11) + r] =
                make_uint2(j[e] & 8191u, __float_as_uint(v[e]));
    }
}

// 1024 blocks x 1024 threads; block = one 8192-leaf bin. Last block done
// (atomic ticket, fence-free) also runs the root tail.
__global__ __launch_bounds__(1024)
void merge_kernel(const float* __restrict__ tree,
                  const uint* __restrict__ cnt,
                  const uint2* __restrict__ bins,
                  uint* __restrict__ l13v,
                  uint* __restrict__ l13f,
                  uint* __restrict__ done,
                  float* __restrict__ out, int C) {
    __shared__ float slv[8192];     // 32 KB
    __shared__ uint  sflb[256];     // 1 KB: 1 dirty bit per leaf slot
    __shared__ float s9v[16];
    __shared__ uint  s9d[16];
    __shared__ uint  sticket;
    __shared__ float s16v[16];
    __shared__ uint  s16d[16];

    const int b    = blockIdx.x;
    const int tid  = threadIdx.x;
    const int wv   = tid >> 6;
    const int lane = tid & 63;
    const int r    = b * 16 + wv;       // 512-leaf region id
    const int leaf0  = tid * 8;
    const int gleaf0 = b * 8192 + leaf0;

    // ---- issue ALL address-predetermined loads up front (one round trip,
    //      drained together at barrier 1) ----
    uint c = cnt[b];
    float4 ta = *(const float4*)(tree + C + gleaf0);
    float4 tb = *(const float4*)(tree + C + gleaf0 + 4);
    float4 t1 = *(const float4*)(tree + (C >> 1) + (gleaf0 >> 1));
    float2 t2 = *(const float2*)(tree + (C >> 2) + (gleaf0 >> 2));
    float t3v = tree[(C >> 3) + (gleaf0 >> 3)];
    float pt[6];                        // L4..L9 ladder values, lane-clamped
    #pragma unroll
    for (int lvl = 4; lvl <= 9; ++lvl) {
        int n = 64 >> (lvl - 3);
        pt[lvl - 4] = tree[(C >> lvl) + (r << (9 - lvl)) + (lane & (n - 1))];
    }
    float pu[4] = {0.f, 0.f, 0.f, 0.f}; // wave0: L10..L13 values
    if (wv == 0) {
        #pragma unroll
        for (int lvl = 10; lvl <= 13; ++lvl) {
            int n = 1 << (13 - lvl);    // 8,4,2,1
            pu[lvl - 10] =
                tree[(C >> lvl) + (b << (13 - lvl)) + (lane & (n - 1))];
        }
    }

    if (tid < 256) sflb[tid] = 0u;
    __syncthreads();                    // barrier 1 (drains hoisted loads)

    if (c > BCAP) c = BCAP;
    const uint2* mybin = bins + ((size_t)b << 11);
    for (uint k = tid; k < c; k += 1024u) {
        uint2 e = mybin[k];
        slv[e.x] = __uint_as_float(e.y);
        atomicOr(&sflb[e.x >> 5], 1u << (e.x & 31u));
    }
    __syncthreads();                    // barrier 2 (drains gather)

    // 8 dirty bits for this thread's leaves: word tid>>2, byte tid&3.
    uint fw8 = (sflb[tid >> 2] >> ((tid & 3) * 8)) & 0xFFu;
    float4 la = *(const float4*)&slv[leaf0];
    float4 lb = *(const float4*)&slv[leaf0 + 4];

    float l0 = (fw8 &   1u) ? la.x : ta.x;
    float l1 = (fw8 &   2u) ? la.y : ta.y;
    float l2 = (fw8 &   4u) ? la.z : ta.z;
    float l3 = (fw8 &   8u) ? la.w : ta.w;
    float l4 = (fw8 &  16u) ? lb.x : tb.x;
    float l5 = (fw8 &  32u) ? lb.y : tb.y;
    float l6 = (fw8 &  64u) ? lb.z : tb.z;
    float l7 = (fw8 & 128u) ? lb.w : tb.w;

    *(float4*)(out + C + gleaf0)     = make_float4(l0, l1, l2, l3);
    *(float4*)(out + C + gleaf0 + 4) = make_float4(l4, l5, l6, l7);

    // ---- L1..L3 in registers (tree values preloaded) ----
    uint d10 = (fw8 &   3u) != 0u;
    uint d11 = (fw8 &  12u) != 0u;
    uint d12 = (fw8 &  48u) != 0u;
    uint d13 = (fw8 & 192u) != 0u;
    float4 v1;
    v1.x = d10 ? l0 + l1 : t1.x;
    v1.y = d11 ? l2 + l3 : t1.y;
    v1.z = d12 ? l4 + l5 : t1.z;
    v1.w = d13 ? l6 + l7 : t1.w;
    *(float4*)(out + (C >> 1) + (gleaf0 >> 1)) = v1;

    uint d20 = d10 | d11, d21 = d12 | d13;
    float2 v2;
    v2.x = d20 ? v1.x + v1.y : t2.x;
    v2.y = d21 ? v1.z + v1.w : t2.y;
    *(float2*)(out + (C >> 2) + (gleaf0 >> 2)) = v2;

    uint d3 = d20 | d21;
    float v = d3 ? v2.x + v2.y : t3v;
    out[(C >> 3) + (gleaf0 >> 3)] = v;

    // ---- L4..L9: wave shuffles, tree values preloaded in pt[] ----
    ull m = __ballot(d3 != 0u);
    #pragma unroll
    for (int lvl = 4; lvl <= 9; ++lvl) {
        float a  = __shfl(v, 2 * lane, 64);
        float bb = __shfl(v, 2 * lane + 1, 64);
        m = pc64(m);
        int n = 64 >> (lvl - 3);
        if (lane < n) {
            int node = (C >> lvl) + (r << (9 - lvl)) + lane;
            uint dd = (uint)(m >> lane) & 1u;
            v = dd ? a + bb : pt[lvl - 4];  // clean nodes carry tree value
            out[node] = v;
        }
    }
    if (lane == 0) { s9v[wv] = v; s9d[wv] = (uint)(m & 1ull); }
    __syncthreads();

    // ---- L10..L13: wave 0 finishes the block's 16 L9 values, then
    //      publishes via device atomics (fence-free) and takes a ticket ----
    if (wv == 0) {
        float vv = lane < 16 ? s9v[lane] : 0.f;
        uint dd  = lane < 16 ? s9d[lane] : 0u;
        ull mm = __ballot(dd != 0u);
        #pragma unroll
        for (int lvl = 10; lvl <= 13; ++lvl) {
            float a  = __shfl(vv, 2 * lane, 64);
            float bb = __shfl(vv, 2 * lane + 1, 64);
            mm = pc64(mm);
            int n = 1 << (13 - lvl);        // 8,4,2,1
            if (lane < n) {
                int node = (C >> lvl) + (b << (13 - lvl)) + lane;
                uint d2 = (uint)(mm >> lane) & 1u;
                vv = d2 ? a + bb : pu[lvl - 10];
                out[node] = vv;
            }
        }
        if (lane == 0) {
            uint o1 = atomicExch(&l13v[b], __float_as_uint(vv));
            uint o2 = atomicExch(&l13f[b], (uint)(mm & 1ull));
            asm volatile("" : : "v"(o1), "v"(o2));   // wait for completion
            sticket = atomicAdd(done, 1u);
        }
    }
    __syncthreads();
    if (sticket != (uint)gridDim.x - 1u) return;

    // ---- fused tail (last block only): ladder 1024 L13 values to root.
    //      Reads ONLY tree (const input) + atomically-published l13v/l13f.
    {
        const int w2 = tid >> 6;
        float tv = __uint_as_float(atomicOr(&l13v[tid], 0u));  // coherent read
        uint  td = atomicOr(&l13f[tid], 0u);

        ull m2 = __ballot(td != 0u);
        #pragma unroll
        for (int M = 512; M >= 16; M >>= 1) {
            float a  = __shfl(tv, 2 * lane, 64);
            float bb = __shfl(tv, 2 * lane + 1, 64);
            m2 = pc64(m2);
            int nw = M >> 4;
            if (lane < nw) {
                int node = M + nw * w2 + lane;
                uint dd = (uint)(m2 >> lane) & 1u;
                tv = dd ? a + bb : tree[node];
                out[node] = tv;
            }
        }
        if (lane == 0) { s16v[w2] = tv; s16d[w2] = (uint)(m2 & 1ull); }
        __syncthreads();

        if (w2 == 0) {
            float vv2 = lane < 16 ? s16v[lane] : 0.f;
            uint dd2  = lane < 16 ? s16d[lane] : 0u;
            ull mm2 = __ballot(dd2 != 0u);
            #pragma unroll
            for (int M = 8; M >= 1; M >>= 1) {
                float a  = __shfl(vv2, 2 * lane, 64);
                float bb = __shfl(vv2, 2 * lane + 1, 64);
                mm2 = pc64(mm2);
                if (lane < M) {
                    uint d2 = (uint)(mm2 >> lane) & 1u;
                    vv2 = d2 ? a + bb : tree[M + lane];
                    out[M + lane] = vv2;
                }
            }
            if (lane == 0) out[0] = tree[0];
        }
    }
}

extern "C" void kernel_launch(void* const* d_in, const int* in_sizes, int n_in,
                              void* d_out, int out_size, void* d_ws, size_t ws_size,
                              hipStream_t stream) {
    const float* tree    = (const float*)d_in[0];
    const int*   indices = (const int*)d_in[1];
    const float* values  = (const float*)d_in[2];
    float* out = (float*)d_out;

    const int two_cap = in_sizes[0];     // 16,777,216
    const int C       = two_cap >> 1;    // 8,388,608
    const int nupd    = in_sizes[1];     // 1,048,576

    uchar* ws = (uchar*)d_ws;
    uint*  cnt  = (uint*)ws;                 // 4 KB
    uint*  done = (uint*)(ws + 4096);        // 4 B
    uint*  l13v = (uint*)(ws + 8192);        // 4 KB
    uint*  l13f = (uint*)(ws + 12288);       // 4 KB
    uint2* bins = (uint2*)(ws + 32768);      // 16 MB

    (void)hipMemsetAsync(ws, 0, 4160, stream);   // cnt + done
    bin_kernel<<<nupd / 4096, 1024, 0, stream>>>(indices, values, cnt, bins);
    merge_kernel<<<C / 8192, 1024, 0, stream>>>(tree, cnt, bins, l13v, l13f,
                                                done, out, C);
}